// Round 6
// baseline (122.903 us; speedup 1.0000x reference)
//
#include <hip/hip_runtime.h>
#include <hip/hip_bf16.h>

// RNN_73048803770905: fused [B,T,200]x[200,64] projection + 128-step tanh RNN + sigmoid head.
// B=4096, T=128, D_IN=200, H=64. 419 MB x read once; HBM floor ~67us.
// R6: R1-R5 plateau = instruction-overhead equilibrium (VALU+LDS pipes saturated at
// 2 blk/CU), not HBM. Cuts: (1) no LDS stage - x loads go straight to VGPR in frag
// layout; (2) proj A-tile packs 8 batch rows x 2 timesteps -> per-byte MFMA/cvt/xp
// cost halves (chunk = 8 t); (3) 512 blocks, 2 blocks/CU, VGPR<=256, LDS ~20KB.
// Cooperative: wave w projects t=8c+2w..+1, owns h-cols w*16..w*16+15 in recurrence.

#define TSEQ 128
#define DIN  200
#define HID  64
#define NB   8
#define TC   8
#define NCH  (TSEQ/TC)   // 16

typedef short bf16x8 __attribute__((ext_vector_type(8)));
typedef float f32x4  __attribute__((ext_vector_type(4)));

__device__ __forceinline__ unsigned short f2bf(float f) {
  __hip_bfloat16 h = __float2bfloat16(f);
  return __builtin_bit_cast(unsigned short, h);
}
__device__ __forceinline__ bf16x8 cvt8(f32x4 a, f32x4 b) {
  bf16x8 r;
#pragma unroll
  for (int i = 0; i < 4; ++i) { r[i] = (short)f2bf(a[i]); r[4 + i] = (short)f2bf(b[i]); }
  return r;
}
// tanh(x) = 1 - 2/(1 + 2^(x*2/ln2)); v_exp_f32 handles the extremes.
__device__ __forceinline__ float tanh_fast(float x) {
  float e = exp2f(x * 2.885390081777927f);
  float r = __builtin_amdgcn_rcpf(1.f + e);
  return __builtin_fmaf(-2.f, r, 1.f);
}
// LDS-only barrier: does NOT drain vmcnt -> in-flight x loads survive the barrier.
__device__ __forceinline__ void barrier_lds() {
  asm volatile("s_waitcnt lgkmcnt(0)" ::: "memory");
  __builtin_amdgcn_s_barrier();
  __builtin_amdgcn_sched_barrier(0);
}

__global__ __launch_bounds__(256, 2) void rnn_fused(
    const float* __restrict__ x,   const float* __restrict__ Wih,
    const float* __restrict__ Whh, const float* __restrict__ bih,
    const float* __restrict__ bhh, const float* __restrict__ Wout,
    const float* __restrict__ bout, float* __restrict__ out)
{
  __shared__ float          xp[TC][NB][68];    // xp chunk f32 (+ final h): 17.4 KB
  __shared__ unsigned short hbuf[2][NB][76];   // h dbuf bf16 bits, stride-padded: 2.4 KB

  const int tid  = threadIdx.x;
  const int w    = tid >> 6;
  const int lane = tid & 63;
  const int m    = lane & 15;
  const int g    = lane >> 4;
  const int b0   = blockIdx.x * NB;

  // proj A-tile row m = (tsub = m>>3, batch = m&7); wave w covers t = 8c + 2w + tsub
  const float* xbase = x + ((size_t)(b0 + (m & 7)) * TSEQ + 2 * w + (m >> 3)) * DIN;

  f32x4 pre[7][2];
  pre[6][0] = (f32x4)0.f; pre[6][1] = (f32x4)0.f;   // g>0 tail stays zero forever
  auto LOADC = [&](int c) {
    const float* p = xbase + (size_t)c * (TC * DIN);
#pragma unroll
    for (int ks = 0; ks < 6; ++ks) {
      const int d = ks * 32 + g * 8;
      pre[ks][0] = *reinterpret_cast<const f32x4*>(p + d);
      pre[ks][1] = *reinterpret_cast<const f32x4*>(p + d + 4);
    }
    if (g == 0) {   // ks=6: d=192..199 only
      pre[6][0] = *reinterpret_cast<const f32x4*>(p + 192);
      pre[6][1] = *reinterpret_cast<const f32x4*>(p + 196);
    }
  };
  LOADC(0);

  // ---- weights into registers ----
  bf16x8 wihf[4][7];   // B[k=d][n=h]: lane h = nt*16+m, d = ks*32+g*8+j
#pragma unroll
  for (int nt = 0; nt < 4; ++nt) {
    const float* wr = Wih + (size_t)(nt * 16 + m) * DIN;
#pragma unroll
    for (int ks = 0; ks < 7; ++ks) {
      const int d = ks * 32 + g * 8;
      if (d + 8 <= DIN)
        wihf[nt][ks] = cvt8(*reinterpret_cast<const f32x4*>(wr + d),
                            *reinterpret_cast<const f32x4*>(wr + d + 4));
      else
        wihf[nt][ks] = (bf16x8)0;
    }
  }
  bf16x8 whhf[2];      // B[k][n=h]: wave owns n-tile w (h = w*16+m), k = hf*32+g*8+j
#pragma unroll
  for (int hf = 0; hf < 2; ++hf) {
    const float* wr = Whh + (size_t)(w * 16 + m) * HID + hf * 32 + g * 8;
    whhf[hf] = cvt8(*reinterpret_cast<const f32x4*>(wr),
                    *reinterpret_cast<const f32x4*>(wr + 4));
  }
  float biasv[4];
#pragma unroll
  for (int nt = 0; nt < 4; ++nt) biasv[nt] = bih[nt * 16 + m] + bhh[nt * 16 + m];

  // zero h state (h_{-1} = 0): 2*8*76 u16 = 608 u32
  for (int i = tid; i < 608; i += 256)
    reinterpret_cast<unsigned int*>(&hbuf[0][0][0])[i] = 0u;
  barrier_lds();

  for (int c = 0; c < NCH; ++c) {
    // ---- proj: 2 timesteps x 8 rows per A-tile; cvt in-loop (small VGPR peak)
    f32x4 acc[4];
#pragma unroll
    for (int nt = 0; nt < 4; ++nt) acc[nt] = (f32x4)(biasv[nt]);
#pragma unroll
    for (int ks = 0; ks < 7; ++ks) {
      bf16x8 a = cvt8(pre[ks][0], pre[ks][1]);   // vmcnt wait for chunk c lands here
#pragma unroll
      for (int nt = 0; nt < 4; ++nt)
        acc[nt] = __builtin_amdgcn_mfma_f32_16x16x32_bf16(a, wihf[nt][ks], acc[nt], 0, 0, 0);
    }
    // pre[] consumed -> refill with chunk c+1 (in flight through the 8 steps)
    if (c + 1 < NCH) LOADC(c + 1);

    // D: col = nt*16+m, row = g*4+rr -> tsub = g>>1, batch = (g&1)*4+rr
#pragma unroll
    for (int nt = 0; nt < 4; ++nt)
#pragma unroll
      for (int rr = 0; rr < 4; ++rr)
        xp[2 * w + (g >> 1)][(g & 1) * 4 + rr][nt * 16 + m] = acc[nt][rr];
    barrier_lds();

    // ---- recurrence: 8 steps; wave owns h cols w*16..w*16+15
#pragma unroll
    for (int tl = 0; tl < TC; ++tl) {
      const int tt = c * TC + tl;
      const int rb = tt & 1, pb = rb ^ 1;
      // A rows: batch = m&7 (rows 8-15 duplicate, D rows 8-15 discarded)
      bf16x8 ha0 = *reinterpret_cast<const bf16x8*>(&hbuf[pb][m & 7][g * 8]);
      bf16x8 ha1 = *reinterpret_cast<const bf16x8*>(&hbuf[pb][m & 7][32 + g * 8]);
      f32x4 racc;
#pragma unroll
      for (int r = 0; r < 4; ++r) racc[r] = xp[tl][(g & 1) * 4 + r][w * 16 + m];
      racc = __builtin_amdgcn_mfma_f32_16x16x32_bf16(ha0, whhf[0], racc, 0, 0, 0);
      racc = __builtin_amdgcn_mfma_f32_16x16x32_bf16(ha1, whhf[1], racc, 0, 0, 0);
      if (g < 2) {   // valid D rows 0-7
#pragma unroll
        for (int r = 0; r < 4; ++r) {
          const float hv = tanh_fast(racc[r]);
          hbuf[rb][g * 4 + r][w * 16 + m] = f2bf(hv);
          if (tt == TSEQ - 1) xp[0][g * 4 + r][w * 16 + m] = hv;   // final h, f32
        }
      }
      barrier_lds();
    }
  }

  // ---- epilogue: out[b] = sigmoid(h_last . Wout + bout) ----
  if (tid < 64) {
    const int b  = lane >> 3;        // 0..7
    const int j0 = (lane & 7) * 8;   // 0..56
    float s = 0.f;
#pragma unroll
    for (int j = 0; j < 8; ++j) s += xp[0][b][j0 + j] * Wout[j0 + j];
    s += __shfl_xor(s, 1, 64);
    s += __shfl_xor(s, 2, 64);
    s += __shfl_xor(s, 4, 64);
    if ((lane & 7) == 0) {
      const float z = s + bout[0];
      out[b0 + b] = __builtin_amdgcn_rcpf(1.f + exp2f(-z * 1.4426950408889634f));
    }
  }
}

extern "C" void kernel_launch(void* const* d_in, const int* in_sizes, int n_in,
                              void* d_out, int out_size, void* d_ws, size_t ws_size,
                              hipStream_t stream) {
  const float* x    = (const float*)d_in[0];
  const float* Wih  = (const float*)d_in[1];
  const float* Whh  = (const float*)d_in[2];
  const float* bih  = (const float*)d_in[3];
  const float* bhh  = (const float*)d_in[4];
  const float* Wout = (const float*)d_in[5];
  const float* bout = (const float*)d_in[6];
  float* out = (float*)d_out;

  const int B = in_sizes[0] / (TSEQ * DIN);   // 4096
  rnn_fused<<<dim3(B / NB), dim3(256), 0, stream>>>(x, Wih, Whh, bih, bhh, Wout, bout, out);
}

// Round 8
// 117.067 us; speedup vs baseline: 1.0499x; 1.0499x over previous
//
#include <hip/hip_runtime.h>
#include <hip/hip_bf16.h>

// RNN_73048803770905: fused [B,T,200]x[200,64] projection + 128-step tanh RNN + sigmoid head.
// B=4096, T=128, D_IN=200, H=64. 419 MB x read once; HBM floor ~67us.
// R8: occupancy attack, conservative rebuild of R7. 1 row/wave (4096 waves, 3/SIMD via
// launch_bounds(256,3)), chunk = 16 timesteps = 16 DISTINCT proj A-rows, acc-as-C,
// h double-buffered per wave with compiler fences around each step's LDS ops,
// A/B k>=200 tail explicitly zeroed, epilogue from regs. Zero in-loop barriers.

#define TSEQ 128
#define DIN  200
#define HID  64
#define CT   16
#define NCH  (TSEQ/CT)   // 8

typedef short bf16x8 __attribute__((ext_vector_type(8)));
typedef float f32x4  __attribute__((ext_vector_type(4)));

__device__ __forceinline__ unsigned short f2bf(float f) {
  __hip_bfloat16 h = __float2bfloat16(f);
  return __builtin_bit_cast(unsigned short, h);
}
__device__ __forceinline__ bf16x8 cvt8(f32x4 a, f32x4 b) {
  bf16x8 r;
#pragma unroll
  for (int i = 0; i < 4; ++i) { r[i] = (short)f2bf(a[i]); r[4 + i] = (short)f2bf(b[i]); }
  return r;
}
// tanh(x) = 1 - 2/(1 + 2^(x*2/ln2)); v_exp_f32 handles the extremes.
__device__ __forceinline__ float tanh_fast(float x) {
  float e = exp2f(x * 2.885390081777927f);
  float r = __builtin_amdgcn_rcpf(1.f + e);
  return __builtin_fmaf(-2.f, r, 1.f);
}

__global__ __launch_bounds__(256, 3) void rnn_fused(
    const float* __restrict__ x,   const float* __restrict__ Wih,
    const float* __restrict__ Whh, const float* __restrict__ bih,
    const float* __restrict__ bhh, const float* __restrict__ Wout,
    const float* __restrict__ bout, float* __restrict__ out)
{
  __shared__ unsigned short wihL[28][64][8];   // Wih bf16 frags, shared: 28 KB
  __shared__ unsigned short hb[4][2][80];      // per-wave h double buffer: 1.25 KB

  const int tid  = threadIdx.x;
  const int w    = tid >> 6;
  const int lane = tid & 63;
  const int m    = lane & 15;
  const int g    = lane >> 4;
  const int row  = blockIdx.x * 4 + w;         // 1024 blocks, 1 batch row per wave

  // A-frag loads: lane (g,m) holds x[row][t = 16c + m][k = ks*32 + g*8 + j], ks=0..6.
  const float* xl = x + ((size_t)row * TSEQ + m) * DIN;

  f32x4 px[7][2];
  auto LOADC = [&](int c) {
    const float* p = xl + (size_t)c * (CT * DIN);
#pragma unroll
    for (int ks = 0; ks < 6; ++ks) {
      const int d = ks * 32 + g * 8;
      px[ks][0] = *reinterpret_cast<const f32x4*>(p + d);
      px[ks][1] = *reinterpret_cast<const f32x4*>(p + d + 4);
    }
    // ks=6 tail d=192..199, loaded by all lanes; zeroed at cvt for g>0
    px[6][0] = *reinterpret_cast<const f32x4*>(p + 192);
    px[6][1] = *reinterpret_cast<const f32x4*>(p + 196);
  };
  LOADC(0);   // chunk 0 in flight during init

  // ---- shared Wih frags (R4-proven): frag f = nt*7+ks; lane = Wih[nt*16+m][ks*32+g*8..+7]
  for (int f = w; f < 28; f += 4) {
    const int nt = f / 7, ks = f % 7;
    const int d  = ks * 32 + g * 8;
    bf16x8 v = (bf16x8)0;
    if (d + 8 <= DIN) {
      const float* wr = Wih + (size_t)(nt * 16 + m) * DIN + d;
      v = cvt8(*reinterpret_cast<const f32x4*>(wr), *reinterpret_cast<const f32x4*>(wr + 4));
    }
    *reinterpret_cast<bf16x8*>(&wihL[f][lane][0]) = v;
  }

  // ---- Whh frags in regs (32 VGPR): B[k][n=h], lane n = nt*16+m, k = hf*32+g*8+j
  bf16x8 whhf[4][2];
#pragma unroll
  for (int nt = 0; nt < 4; ++nt)
#pragma unroll
    for (int hf = 0; hf < 2; ++hf) {
      const float* wr = Whh + (size_t)(nt * 16 + m) * HID + hf * 32 + g * 8;
      whhf[nt][hf] = cvt8(*reinterpret_cast<const f32x4*>(wr),
                          *reinterpret_cast<const f32x4*>(wr + 4));
    }
  float biasv[4], woutv[4];
#pragma unroll
  for (int nt = 0; nt < 4; ++nt) {
    biasv[nt] = bih[nt * 16 + m] + bhh[nt * 16 + m];
    woutv[nt] = Wout[nt * 16 + m];
  }
  const float bout0 = bout[0];

  hb[w][0][lane] = 0;   // h_{-1} = 0; t=0 reads buf 1
  hb[w][1][lane] = 0;
  __syncthreads();      // wihL ready; ONLY barrier in the kernel

  float vfin[4] = {0.f, 0.f, 0.f, 0.f};   // final h, valid on g==3 lanes

  for (int c = 0; c < NCH; ++c) {
    // ---- cvt A-frags (vmcnt wait for chunk c lands here); px dead afterwards
    bf16x8 afr[7];
#pragma unroll
    for (int ks = 0; ks < 6; ++ks) afr[ks] = cvt8(px[ks][0], px[ks][1]);
    afr[6] = (g == 0) ? cvt8(px[6][0], px[6][1]) : (bf16x8)0;   // k>=200 zero (matches B)

    // ---- proj: acc = x_tile * Wih^T + bias; D rows = 16 timesteps; acc stays as C
    f32x4 acc[4];
#pragma unroll
    for (int nt = 0; nt < 4; ++nt) acc[nt] = (f32x4)(biasv[nt]);
#pragma unroll
    for (int ks = 0; ks < 7; ++ks) {
#pragma unroll
      for (int nt = 0; nt < 4; ++nt) {
        bf16x8 bv = *reinterpret_cast<const bf16x8*>(&wihL[nt * 7 + ks][lane][0]);
        acc[nt] = __builtin_amdgcn_mfma_f32_16x16x32_bf16(afr[ks], bv, acc[nt], 0, 0, 0);
      }
    }

    if (c + 1 < NCH) LOADC(c + 1);   // refill px; in flight across the 16 steps

    // ---- 16 recurrence steps, fully in-wave. A = h_{t-1} broadcast to all 16 rows
    // (uniform conflict-free ds_read); D row s valid at lane group g = s>>2, reg s&3.
#pragma unroll
    for (int s = 0; s < CT; ++s) {
      const int rb = s & 1, pb = rb ^ 1;   // compile-time parity (CT even)
      asm volatile("" ::: "memory");       // fence: no reordering of h LDS ops
      bf16x8 ha0 = *reinterpret_cast<const bf16x8*>(&hb[w][pb][g * 8]);        // k 0..31
      bf16x8 ha1 = *reinterpret_cast<const bf16x8*>(&hb[w][pb][32 + g * 8]);   // k 32..63
      f32x4 racc[4];
#pragma unroll
      for (int nt = 0; nt < 4; ++nt)
        racc[nt] = __builtin_amdgcn_mfma_f32_16x16x32_bf16(ha0, whhf[nt][0], acc[nt], 0, 0, 0);
#pragma unroll
      for (int nt = 0; nt < 4; ++nt)
        racc[nt] = __builtin_amdgcn_mfma_f32_16x16x32_bf16(ha1, whhf[nt][1], racc[nt], 0, 0, 0);
      if (g == (s >> 2)) {                 // the one group holding D row s
#pragma unroll
        for (int nt = 0; nt < 4; ++nt) {
          const float v = tanh_fast(racc[nt][s & 3]);
          hb[w][rb][nt * 16 + m] = f2bf(v);          // 16 lanes x 4 cols = all 64
          if (s == CT - 1) vfin[nt] = v;
        }
      }
      asm volatile("" ::: "memory");
    }
  }

  // ---- epilogue: g==3 lanes hold final h; reduce within the 16-lane group
  float sred = vfin[0] * woutv[0] + vfin[1] * woutv[1]
             + vfin[2] * woutv[2] + vfin[3] * woutv[3];
  sred += __shfl_xor(sred, 1, 64);
  sred += __shfl_xor(sred, 2, 64);
  sred += __shfl_xor(sred, 4, 64);
  sred += __shfl_xor(sred, 8, 64);
  if (lane == 48)
    out[row] = __builtin_amdgcn_rcpf(1.f + exp2f(-(sred + bout0) * 1.4426950408889634f));
}

extern "C" void kernel_launch(void* const* d_in, const int* in_sizes, int n_in,
                              void* d_out, int out_size, void* d_ws, size_t ws_size,
                              hipStream_t stream) {
  const float* x    = (const float*)d_in[0];
  const float* Wih  = (const float*)d_in[1];
  const float* Whh  = (const float*)d_in[2];
  const float* bih  = (const float*)d_in[3];
  const float* bhh  = (const float*)d_in[4];
  const float* Wout = (const float*)d_in[5];
  const float* bout = (const float*)d_in[6];
  float* out = (float*)d_out;

  const int B = in_sizes[0] / (TSEQ * DIN);   // 4096
  rnn_fused<<<dim3(B / 4), dim3(256), 0, stream>>>(x, Wih, Whh, bih, bhh, Wout, bout, out);
}